// Round 7
// baseline (729.479 us; speedup 1.0000x reference)
//
#include <hip/hip_runtime.h>
#include <hip/hip_bf16.h>

// adLIF: Wx = x @ W^T (fp32 FMA GEMM, strictly sequential-K accumulation to
// mirror BLAS bit-for-bit), then sequential LIF scan over T with rounding-exact
// fp32 ops. Input dtype (fp32 vs bf16) detected ON DEVICE from x's bit pattern.
// GEMM: r6 structure (128x128 tile, 8x8 micro, VGPR~116, LSTR=132 padding),
//       epilogue TRANSPOSED: ws = Wx in [B, H, T] layout (t-contiguous).
// Scan: barrier-free, LDS-free: each thread streams its 512-float t-row with a
//       4-chunk register ring; coalesced [B,T,H] output stores.

#define M_SZ 65536  // B*T
#define H_SZ 512
#define K_SZ 512
#define B_SZ 128
#define T_SZ 512
#define LSTR 132  // LDS row stride (dwords), %32==4: staging writes conflict-free

typedef __attribute__((ext_vector_type(4))) float f32x4;

__device__ __forceinline__ bool detect_bf16(const unsigned int* __restrict__ w) {
  int c = 0;
#pragma unroll
  for (int i = 0; i < 64; ++i) {
    unsigned int e = (w[i] >> 7) & 0xffu;
    c += (e >= 115u && e <= 131u) ? 1 : 0;
  }
  return c > 32;  // bf16 exponents cluster in [115,131]; fp32 mantissa bits don't
}

template <bool ISB>
__device__ __forceinline__ f32x4 ld4t(const void* __restrict__ p, size_t off) {
  if constexpr (!ISB) {
    return *reinterpret_cast<const f32x4*>(reinterpret_cast<const float*>(p) + off);
  } else {
    uint2 v = *reinterpret_cast<const uint2*>(reinterpret_cast<const unsigned short*>(p) + off);
    f32x4 r;
    r.x = __uint_as_float((v.x & 0xffffu) << 16);
    r.y = __uint_as_float(v.x & 0xffff0000u);
    r.z = __uint_as_float((v.y & 0xffffu) << 16);
    r.w = __uint_as_float(v.y & 0xffff0000u);
    return r;
  }
}

template <bool ISB>
__device__ __forceinline__ float ld1t(const void* __restrict__ p, int i) {
  if constexpr (!ISB) return reinterpret_cast<const float*>(p)[i];
  return __uint_as_float((unsigned int)(reinterpret_cast<const unsigned short*>(p)[i]) << 16);
}

// ---------------- GEMM: Cт[b][n][t] = sum_k X[m][k]*W[n][k], m=b*512+t -------
template <bool ISB>
__device__ __forceinline__ void gemm_body(const void* __restrict__ X,
                                          const void* __restrict__ Wm,
                                          float* __restrict__ C,
                                          float* __restrict__ As,
                                          float* __restrict__ Bs) {
  const int tid = threadIdx.x;
  const int r0 = tid >> 2;       // 0..63: staged row
  const int q0 = (tid & 3) * 4;  // 0,4,8,12: k-group
  const int tx = tid & 15;       // n-group
  const int ty = tid >> 4;       // m-group
  const size_t M0 = (size_t)(blockIdx.x >> 2) * 128;
  const int N0 = (blockIdx.x & 3) * 128;

  float acc[8][8];
#pragma unroll
  for (int i = 0; i < 8; ++i)
#pragma unroll
    for (int j = 0; j < 8; ++j) acc[i][j] = 0.0f;

  const size_t aoff0 = (M0 + r0) * K_SZ + q0;
  const size_t aoff1 = (M0 + r0 + 64) * K_SZ + q0;
  const size_t boff0 = (size_t)(N0 + r0) * K_SZ + q0;
  const size_t boff1 = (size_t)(N0 + r0 + 64) * K_SZ + q0;

  f32x4 pa0 = ld4t<ISB>(X, aoff0), pa1 = ld4t<ISB>(X, aoff1);
  f32x4 pb0 = ld4t<ISB>(Wm, boff0), pb1 = ld4t<ISB>(Wm, boff1);

  for (int kk = 0; kk < K_SZ; kk += 16) {
    __syncthreads();  // prior compute done -> LDS free
    As[(q0 + 0) * LSTR + r0] = pa0.x; As[(q0 + 1) * LSTR + r0] = pa0.y;
    As[(q0 + 2) * LSTR + r0] = pa0.z; As[(q0 + 3) * LSTR + r0] = pa0.w;
    As[(q0 + 0) * LSTR + r0 + 64] = pa1.x; As[(q0 + 1) * LSTR + r0 + 64] = pa1.y;
    As[(q0 + 2) * LSTR + r0 + 64] = pa1.z; As[(q0 + 3) * LSTR + r0 + 64] = pa1.w;
    Bs[(q0 + 0) * LSTR + r0] = pb0.x; Bs[(q0 + 1) * LSTR + r0] = pb0.y;
    Bs[(q0 + 2) * LSTR + r0] = pb0.z; Bs[(q0 + 3) * LSTR + r0] = pb0.w;
    Bs[(q0 + 0) * LSTR + r0 + 64] = pb1.x; Bs[(q0 + 1) * LSTR + r0 + 64] = pb1.y;
    Bs[(q0 + 2) * LSTR + r0 + 64] = pb1.z; Bs[(q0 + 3) * LSTR + r0 + 64] = pb1.w;
    __syncthreads();  // tile ready
    if (kk + 16 < K_SZ) {  // prefetch next chunk; in flight across compute
      pa0 = ld4t<ISB>(X, aoff0 + kk + 16); pa1 = ld4t<ISB>(X, aoff1 + kk + 16);
      pb0 = ld4t<ISB>(Wm, boff0 + kk + 16); pb1 = ld4t<ISB>(Wm, boff1 + kk + 16);
    }
#pragma unroll
    for (int k = 0; k < 16; ++k) {
      const f32x4 a0 = *reinterpret_cast<const f32x4*>(As + k * LSTR + ty * 4);
      const f32x4 a1 = *reinterpret_cast<const f32x4*>(As + k * LSTR + 64 + ty * 4);
      const f32x4 b0 = *reinterpret_cast<const f32x4*>(Bs + k * LSTR + tx * 4);
      const f32x4 b1 = *reinterpret_cast<const f32x4*>(Bs + k * LSTR + 64 + tx * 4);
      const float av[8] = {a0.x, a0.y, a0.z, a0.w, a1.x, a1.y, a1.z, a1.w};
      const float bv[8] = {b0.x, b0.y, b0.z, b0.w, b1.x, b1.y, b1.z, b1.w};
#pragma unroll
      for (int i = 0; i < 8; ++i)
#pragma unroll
        for (int j = 0; j < 8; ++j) acc[i][j] += av[i] * bv[j];  // contracts to FMA
    }
  }

  // Transposed epilogue: C[b][n][t]; for fixed n, acc[0..3][j] are 4 consecutive
  // t (t = t0b + ty*4 + r) -> f32x4 stores along t. Plain stores: 4 blocks'
  // worth of each 64B line come from this block's epilogue -> L2 combines.
  const int b = (int)(M0 >> 9);
  const int t0b = (int)(M0 & 511);
#pragma unroll
  for (int j = 0; j < 8; ++j) {
    const int n = N0 + ((j < 4) ? (tx * 4 + j) : (64 + tx * 4 + (j - 4)));
    float* cp = C + ((size_t)b * H_SZ + n) * T_SZ + t0b;
    f32x4 vlo = {acc[0][j], acc[1][j], acc[2][j], acc[3][j]};
    f32x4 vhi = {acc[4][j], acc[5][j], acc[6][j], acc[7][j]};
    *reinterpret_cast<f32x4*>(cp + ty * 4) = vlo;
    *reinterpret_cast<f32x4*>(cp + 64 + ty * 4) = vhi;
  }
}

__global__ __launch_bounds__(256) void sgemm_bt(const void* __restrict__ X,
                                                const void* __restrict__ Wm,
                                                float* __restrict__ C) {
  __shared__ float As[16 * LSTR];  // 8.45 KB
  __shared__ float Bs[16 * LSTR];  // 8.45 KB
  if (detect_bf16(reinterpret_cast<const unsigned int*>(X)))
    gemm_body<true>(X, Wm, C, As, Bs);
  else
    gemm_body<false>(X, Wm, C, As, Bs);
}

// ---------------- LIF scan: contiguous per-thread t-stream, register ring ----
// wxT is [B,H,T]; thread (b,h) reads 512 consecutive floats. Ring of 4 chunks
// (8 t each) = 32-t lookahead, ~16 KB in flight per CU. No LDS, no barriers.
template <bool ISB>
__device__ __forceinline__ void scan_body(
    const float* __restrict__ wxT, const void* __restrict__ alpha_p,
    const void* __restrict__ beta_p, const void* __restrict__ a_p,
    const void* __restrict__ b_p, const void* __restrict__ u0p,
    const void* __restrict__ w0p, const void* __restrict__ s0p,
    void* __restrict__ out) {
  const int tid = threadIdx.x;        // 0..127
  const int bb = blockIdx.x >> 2;     // batch
  const int quarter = blockIdx.x & 3;
  const int h = quarter * 128 + tid;

  const float al = fminf(fmaxf(ld1t<ISB>(alpha_p, h), (float)0.8187307530779818),
                         (float)0.9607894391523232);
  const float be = fminf(fmaxf(ld1t<ISB>(beta_p, h), (float)0.9672161004820059),
                         (float)0.9917013044213351);
  const float av = fminf(fmaxf(ld1t<ISB>(a_p, h), -1.0f), 1.0f);
  const float bv = fminf(fmaxf(ld1t<ISB>(b_p, h), 0.0f), 2.0f);
  const float om = __fsub_rn(1.0f, al);

  const int bh = bb * H_SZ + h;
  float u = ld1t<ISB>(u0p, bh);
  float w = ld1t<ISB>(w0p, bh);
  float s = ld1t<ISB>(s0p, bh);

  const float* base = wxT + ((size_t)bb * H_SZ + h) * T_SZ;  // contiguous 512
  float* outf = reinterpret_cast<float*>(out);
  __hip_bfloat16* outb = reinterpret_cast<__hip_bfloat16*>(out);
  const size_t ob0 = (size_t)bb * T_SZ * H_SZ + h;

  f32x4 ring[8];  // 4 chunks x 2 vectors (8 t per chunk)
#pragma unroll
  for (int c = 0; c < 4; ++c) {
    ring[2 * c] = *reinterpret_cast<const f32x4*>(base + c * 8);
    ring[2 * c + 1] = *reinterpret_cast<const f32x4*>(base + c * 8 + 4);
  }

  for (int c0 = 0; c0 < T_SZ / 8; c0 += 4) {
#pragma unroll
    for (int c2 = 0; c2 < 4; ++c2) {
      const int c = c0 + c2;
      const f32x4 v0 = ring[2 * c2];
      const f32x4 v1 = ring[2 * c2 + 1];
      if (c + 4 < T_SZ / 8) {  // reload slot for chunk c+4 (32-t lookahead)
        ring[2 * c2] = *reinterpret_cast<const f32x4*>(base + (c + 4) * 8);
        ring[2 * c2 + 1] = *reinterpret_cast<const f32x4*>(base + (c + 4) * 8 + 4);
      }
      const float cur[8] = {v0.x, v0.y, v0.z, v0.w, v1.x, v1.y, v1.z, v1.w};
#pragma unroll
      for (int j = 0; j < 8; ++j) {
        // numpy left-to-right, each op individually rounded (no FMA contraction)
        w = __fadd_rn(__fadd_rn(__fmul_rn(be, w), __fmul_rn(av, u)), __fmul_rn(bv, s));
        u = __fadd_rn(__fmul_rn(al, __fsub_rn(u, s)), __fmul_rn(om, __fsub_rn(cur[j], w)));
        s = (u > 1.0f) ? 1.0f : 0.0f;
        const size_t o = ob0 + (size_t)(c * 8 + j) * H_SZ;  // [B,T,H], h-coalesced
        if constexpr (ISB) outb[o] = __float2bfloat16(s);   // 0/1 exact in bf16
        else outf[o] = s;
      }
    }
  }
}

__global__ __launch_bounds__(128) void lif_scan(
    const float* __restrict__ wxT, const void* __restrict__ X,
    const void* __restrict__ alpha_p, const void* __restrict__ beta_p,
    const void* __restrict__ a_p, const void* __restrict__ b_p,
    const void* __restrict__ u0p, const void* __restrict__ w0p,
    const void* __restrict__ s0p, void* __restrict__ out) {
  if (detect_bf16(reinterpret_cast<const unsigned int*>(X)))
    scan_body<true>(wxT, alpha_p, beta_p, a_p, b_p, u0p, w0p, s0p, out);
  else
    scan_body<false>(wxT, alpha_p, beta_p, a_p, b_p, u0p, w0p, s0p, out);
}

extern "C" void kernel_launch(void* const* d_in, const int* in_sizes, int n_in,
                              void* d_out, int out_size, void* d_ws, size_t ws_size,
                              hipStream_t stream) {
  const void* X = d_in[0];   // x [B,T,I]
  const void* Wm = d_in[1];  // W [H,I]
  float* ws = reinterpret_cast<float*>(d_ws);  // Wx fp32 in [B,H,T] layout

  sgemm_bt<<<dim3((M_SZ / 128) * (H_SZ / 128)), dim3(256), 0, stream>>>(X, Wm, ws);

  lif_scan<<<dim3(B_SZ * 4), dim3(128), 0, stream>>>(
      ws, X, d_in[2], d_in[3], d_in[4], d_in[5], d_in[6], d_in[7], d_in[8], d_out);
}

// Round 9
// 648.585 us; speedup vs baseline: 1.1247x; 1.1247x over previous
//
#include <hip/hip_runtime.h>
#include <hip/hip_bf16.h>

// adLIF: Wx = x @ W^T (fp32 FMA GEMM, strictly sequential-K accumulation to
// mirror BLAS bit-for-bit), then sequential LIF scan over T with rounding-exact
// fp32 ops. Input dtype (fp32 vs bf16) detected ON DEVICE from x's bit pattern.
// GEMM: r6 structure VERBATIM (128x128 tile, 8x8 micro, VGPR 116, LSTR=132,
//       [B,T,H] nontemporal epilogue) - measured 421 us.
// Scan: coalesced-DMA chunks, 4-SLOT ring with lookahead 3 (slot (c+3)%4 !=
//       c%4 -> no producer/consumer collision, unlike r8's 3-slot bug), fused
//       asm "s_waitcnt vmcnt(24); s_barrier" with memory clobber.

#define M_SZ 65536  // B*T
#define H_SZ 512
#define K_SZ 512
#define B_SZ 128
#define T_SZ 512
#define LSTR 132  // LDS row stride (dwords), %32==4: staging writes conflict-free

typedef __attribute__((ext_vector_type(4))) float f32x4;

__device__ __forceinline__ bool detect_bf16(const unsigned int* __restrict__ w) {
  int c = 0;
#pragma unroll
  for (int i = 0; i < 64; ++i) {
    unsigned int e = (w[i] >> 7) & 0xffu;
    c += (e >= 115u && e <= 131u) ? 1 : 0;
  }
  return c > 32;  // bf16 exponents cluster in [115,131]; fp32 mantissa bits don't
}

template <bool ISB>
__device__ __forceinline__ f32x4 ld4t(const void* __restrict__ p, size_t off) {
  if constexpr (!ISB) {
    return *reinterpret_cast<const f32x4*>(reinterpret_cast<const float*>(p) + off);
  } else {
    uint2 v = *reinterpret_cast<const uint2*>(reinterpret_cast<const unsigned short*>(p) + off);
    f32x4 r;
    r.x = __uint_as_float((v.x & 0xffffu) << 16);
    r.y = __uint_as_float(v.x & 0xffff0000u);
    r.z = __uint_as_float((v.y & 0xffffu) << 16);
    r.w = __uint_as_float(v.y & 0xffff0000u);
    return r;
  }
}

template <bool ISB>
__device__ __forceinline__ float ld1t(const void* __restrict__ p, int i) {
  if constexpr (!ISB) return reinterpret_cast<const float*>(p)[i];
  return __uint_as_float((unsigned int)(reinterpret_cast<const unsigned short*>(p)[i]) << 16);
}

__device__ __forceinline__ void gl_lds16(const void* g, void* l) {
  __builtin_amdgcn_global_load_lds(
      (const __attribute__((address_space(1))) void*)g,
      (__attribute__((address_space(3))) void*)l, 16, 0, 0);
}

// ---------------- GEMM: C[m][n] = sum_k X[m][k]*W[n][k], fp32, k ascending ----
template <bool ISB>
__device__ __forceinline__ void gemm_body(const void* __restrict__ X,
                                          const void* __restrict__ Wm,
                                          float* __restrict__ C,
                                          float* __restrict__ As,
                                          float* __restrict__ Bs) {
  const int tid = threadIdx.x;
  const int r0 = tid >> 2;       // 0..63: staged row
  const int q0 = (tid & 3) * 4;  // 0,4,8,12: k-group
  const int tx = tid & 15;       // n-group
  const int ty = tid >> 4;       // m-group
  const size_t M0 = (size_t)(blockIdx.x >> 2) * 128;
  const int N0 = (blockIdx.x & 3) * 128;

  float acc[8][8];
#pragma unroll
  for (int i = 0; i < 8; ++i)
#pragma unroll
    for (int j = 0; j < 8; ++j) acc[i][j] = 0.0f;

  const size_t aoff0 = (M0 + r0) * K_SZ + q0;
  const size_t aoff1 = (M0 + r0 + 64) * K_SZ + q0;
  const size_t boff0 = (size_t)(N0 + r0) * K_SZ + q0;
  const size_t boff1 = (size_t)(N0 + r0 + 64) * K_SZ + q0;

  f32x4 pa0 = ld4t<ISB>(X, aoff0), pa1 = ld4t<ISB>(X, aoff1);
  f32x4 pb0 = ld4t<ISB>(Wm, boff0), pb1 = ld4t<ISB>(Wm, boff1);

  for (int kk = 0; kk < K_SZ; kk += 16) {
    __syncthreads();  // prior compute done -> LDS free
    As[(q0 + 0) * LSTR + r0] = pa0.x; As[(q0 + 1) * LSTR + r0] = pa0.y;
    As[(q0 + 2) * LSTR + r0] = pa0.z; As[(q0 + 3) * LSTR + r0] = pa0.w;
    As[(q0 + 0) * LSTR + r0 + 64] = pa1.x; As[(q0 + 1) * LSTR + r0 + 64] = pa1.y;
    As[(q0 + 2) * LSTR + r0 + 64] = pa1.z; As[(q0 + 3) * LSTR + r0 + 64] = pa1.w;
    Bs[(q0 + 0) * LSTR + r0] = pb0.x; Bs[(q0 + 1) * LSTR + r0] = pb0.y;
    Bs[(q0 + 2) * LSTR + r0] = pb0.z; Bs[(q0 + 3) * LSTR + r0] = pb0.w;
    Bs[(q0 + 0) * LSTR + r0 + 64] = pb1.x; Bs[(q0 + 1) * LSTR + r0 + 64] = pb1.y;
    Bs[(q0 + 2) * LSTR + r0 + 64] = pb1.z; Bs[(q0 + 3) * LSTR + r0 + 64] = pb1.w;
    __syncthreads();  // tile ready
    if (kk + 16 < K_SZ) {  // prefetch next chunk; in flight across compute
      pa0 = ld4t<ISB>(X, aoff0 + kk + 16); pa1 = ld4t<ISB>(X, aoff1 + kk + 16);
      pb0 = ld4t<ISB>(Wm, boff0 + kk + 16); pb1 = ld4t<ISB>(Wm, boff1 + kk + 16);
    }
#pragma unroll
    for (int k = 0; k < 16; ++k) {
      const f32x4 a0 = *reinterpret_cast<const f32x4*>(As + k * LSTR + ty * 4);
      const f32x4 a1 = *reinterpret_cast<const f32x4*>(As + k * LSTR + 64 + ty * 4);
      const f32x4 b0 = *reinterpret_cast<const f32x4*>(Bs + k * LSTR + tx * 4);
      const f32x4 b1 = *reinterpret_cast<const f32x4*>(Bs + k * LSTR + 64 + tx * 4);
      const float av[8] = {a0.x, a0.y, a0.z, a0.w, a1.x, a1.y, a1.z, a1.w};
      const float bv[8] = {b0.x, b0.y, b0.z, b0.w, b1.x, b1.y, b1.z, b1.w};
#pragma unroll
      for (int i = 0; i < 8; ++i)
#pragma unroll
        for (int j = 0; j < 8; ++j) acc[i][j] += av[i] * bv[j];  // contracts to FMA
    }
  }

#pragma unroll
  for (int r = 0; r < 8; ++r) {
    const size_t m = M0 + ((r < 4) ? (ty * 4 + r) : (64 + ty * 4 + (r - 4)));
    float* Cp = C + m * H_SZ + N0;
    f32x4 v0 = {acc[r][0], acc[r][1], acc[r][2], acc[r][3]};
    f32x4 v1 = {acc[r][4], acc[r][5], acc[r][6], acc[r][7]};
    __builtin_nontemporal_store(v0, reinterpret_cast<f32x4*>(Cp + tx * 4));
    __builtin_nontemporal_store(v1, reinterpret_cast<f32x4*>(Cp + 64 + tx * 4));
  }
}

__global__ __launch_bounds__(256) void sgemm_bt(const void* __restrict__ X,
                                                const void* __restrict__ Wm,
                                                float* __restrict__ C) {
  __shared__ float As[16 * LSTR];  // 8.45 KB
  __shared__ float Bs[16 * LSTR];  // 8.45 KB
  if (detect_bf16(reinterpret_cast<const unsigned int*>(X)))
    gemm_body<true>(X, Wm, C, As, Bs);
  else
    gemm_body<false>(X, Wm, C, As, Bs);
}

// ---------------- LIF scan: 4-slot DMA ring (lookahead 3), vmcnt + s_barrier -
// 512 blocks x 128 thr (2 waves); block = (b, 128-h quarter). Chunk = 32 t
// (16 KB); ring of 4 slots (64 KB LDS). Wave wv stages t-rows wv*16..wv*16+15
// of each chunk: 8 DMA instrs x 1 KB (2 contiguous 512 B rows each).
// Per iter: issue(c+3) -> slot (c+3)&3 (never the slot being read, unlike
// r8's 3-slot collision); then fused asm s_waitcnt vmcnt(24) + s_barrier
// (memory clobber stops compiler hoisting LDS reads).
//   FIFO proof (vmcnt retires in order): at iter c's wait, chunk c's DMAs are
//   followed in this wave's stream by >=24 vm-instrs (c=0: D1,D2,D3 = 24
//   exactly; c>=1: + 32 stores per completed iter) -> <=24 outstanding
//   implies chunk c retired. Each wave waits on ITS own DMAs before the
//   barrier; barrier then publishes both waves' halves.
#define SCH 32            // timesteps per chunk
#define NCH (T_SZ / SCH)  // 16
#define NSLOT 4
#define LOOKA 3

template <bool ISB>
__device__ __forceinline__ void scan_body(
    const float* __restrict__ wx, const void* __restrict__ alpha_p,
    const void* __restrict__ beta_p, const void* __restrict__ a_p,
    const void* __restrict__ b_p, const void* __restrict__ u0p,
    const void* __restrict__ w0p, const void* __restrict__ s0p,
    void* __restrict__ out, float* __restrict__ ring) {
  const int tid = threadIdx.x;  // 0..127
  const int wv = tid >> 6;      // 0/1
  const int lane = tid & 63;
  const int bb = blockIdx.x >> 2;
  const int quarter = blockIdx.x & 3;
  const int h = quarter * 128 + tid;

  const float al = fminf(fmaxf(ld1t<ISB>(alpha_p, h), (float)0.8187307530779818),
                         (float)0.9607894391523232);
  const float be = fminf(fmaxf(ld1t<ISB>(beta_p, h), (float)0.9672161004820059),
                         (float)0.9917013044213351);
  const float av = fminf(fmaxf(ld1t<ISB>(a_p, h), -1.0f), 1.0f);
  const float bv = fminf(fmaxf(ld1t<ISB>(b_p, h), 0.0f), 2.0f);
  const float om = __fsub_rn(1.0f, al);

  const int bh = bb * H_SZ + h;
  float u = ld1t<ISB>(u0p, bh);
  float w = ld1t<ISB>(w0p, bh);
  float s = ld1t<ISB>(s0p, bh);

  const float* xb = wx + (size_t)bb * T_SZ * H_SZ + quarter * 128;  // + t*H
  float* outf = reinterpret_cast<float*>(out);
  __hip_bfloat16* outb = reinterpret_cast<__hip_bfloat16*>(out);
  const size_t ob0 = (size_t)bb * T_SZ * H_SZ + h;

  // DMA chunk c into slot c&3: wave wv covers LDS rows wv*16..wv*16+15
  // (t = c*32 + row). Instr i: rows 2i,2i+1 at LDS base dst + 2i*128
  // (wave-uniform); lane l auto-writes +l*16B; global: row 2i+(l>>5),
  // dwords (l&31)*4.. (contiguous 512 B per row).
  auto issue = [&](int c) {
    float* dst = ring + (c & (NSLOT - 1)) * (SCH * 128) + wv * (16 * 128);
    const float* sp = xb + (size_t)(c * SCH + wv * 16) * H_SZ;
#pragma unroll
    for (int i = 0; i < 8; ++i) {
      gl_lds16(sp + (size_t)(2 * i + (lane >> 5)) * H_SZ + (lane & 31) * 4,
               dst + 2 * i * 128);
    }
  };

  issue(0); issue(1); issue(2);

  for (int c = 0; c < NCH; ++c) {
    if (c + LOOKA < NCH) issue(c + LOOKA);  // slot (c+3)&3 != c&3: no collision
    asm volatile("s_waitcnt vmcnt(24)\n\ts_barrier" ::: "memory");
    const float* cb = ring + (c & (NSLOT - 1)) * (SCH * 128);
#pragma unroll 8
    for (int j = 0; j < SCH; ++j) {
      const float cur = cb[j * 128 + tid];
      // numpy left-to-right, each op individually rounded (no FMA contraction)
      w = __fadd_rn(__fadd_rn(__fmul_rn(be, w), __fmul_rn(av, u)), __fmul_rn(bv, s));
      u = __fadd_rn(__fmul_rn(al, __fsub_rn(u, s)), __fmul_rn(om, __fsub_rn(cur, w)));
      s = (u > 1.0f) ? 1.0f : 0.0f;
      const size_t o = ob0 + (size_t)(c * SCH + j) * H_SZ;  // h-coalesced
      if constexpr (ISB) outb[o] = __float2bfloat16(s);     // 0/1 exact in bf16
      else outf[o] = s;
    }
  }
}

__global__ __launch_bounds__(128) void lif_scan(
    const float* __restrict__ wx, const void* __restrict__ X,
    const void* __restrict__ alpha_p, const void* __restrict__ beta_p,
    const void* __restrict__ a_p, const void* __restrict__ b_p,
    const void* __restrict__ u0p, const void* __restrict__ w0p,
    const void* __restrict__ s0p, void* __restrict__ out) {
  __shared__ float ring[NSLOT * SCH * 128];  // 64 KB -> 2 blocks/CU
  if (detect_bf16(reinterpret_cast<const unsigned int*>(X)))
    scan_body<true>(wx, alpha_p, beta_p, a_p, b_p, u0p, w0p, s0p, out, ring);
  else
    scan_body<false>(wx, alpha_p, beta_p, a_p, b_p, u0p, w0p, s0p, out, ring);
}

extern "C" void kernel_launch(void* const* d_in, const int* in_sizes, int n_in,
                              void* d_out, int out_size, void* d_ws, size_t ws_size,
                              hipStream_t stream) {
  const void* X = d_in[0];   // x [B,T,I]
  const void* Wm = d_in[1];  // W [H,I]
  float* ws = reinterpret_cast<float*>(d_ws);  // Wx fp32 [B,T,H]

  sgemm_bt<<<dim3((M_SZ / 128) * (H_SZ / 128)), dim3(256), 0, stream>>>(X, Wm, ws);

  lif_scan<<<dim3(B_SZ * 4), dim3(128), 0, stream>>>(
      ws, X, d_in[2], d_in[3], d_in[4], d_in[5], d_in[6], d_in[7], d_in[8], d_out);
}